// Round 1
// baseline (1600.951 us; speedup 1.0000x reference)
//
#include <hip/hip_runtime.h>
#include <math.h>

#define B    16
#define N    20000
#define E    640000
#define NREG 2000
#define DIN  128
#define F    32
#define NEG  0.2f

// ---------------- histogram of edge endpoints ----------------
__global__ void k_hist(const int* __restrict__ src, const int* __restrict__ dst,
                       int* __restrict__ counts, int* __restrict__ rcounts) {
    int e = blockIdx.x * blockDim.x + threadIdx.x;
    int stride = gridDim.x * blockDim.x;
    for (; e < E; e += stride) {
        atomicAdd(&counts[dst[e]], 1);
        atomicAdd(&rcounts[src[e]], 1);
    }
}

// ---------------- single-block exclusive scan (n <= 1024*chunk) ----------------
__global__ void k_scan(const int* __restrict__ in, int* __restrict__ out, int n) {
    __shared__ int sh[1024];
    int t = threadIdx.x;
    int chunk = (n + 1023) / 1024;
    int lo = t * chunk;
    int hi = lo + chunk; if (hi > n) hi = n;
    int local = 0;
    for (int i = lo; i < hi; ++i) local += in[i];
    sh[t] = local;
    __syncthreads();
    for (int d = 1; d < 1024; d <<= 1) {
        int v = (t >= d) ? sh[t - d] : 0;
        __syncthreads();
        sh[t] += v;
        __syncthreads();
    }
    int run = (t == 0) ? 0 : sh[t - 1];
    for (int i = lo; i < hi; ++i) { out[i] = run; run += in[i]; }
    if (t == 1023) out[n] = sh[1023];
}

// ---------------- scatter edges into CSR-by-dst ----------------
__global__ void k_scatter(const int* __restrict__ src, const int* __restrict__ dst,
                          const int* __restrict__ off, int* __restrict__ cursor,
                          int* __restrict__ csr_src, int* __restrict__ csr_eid) {
    int e = blockIdx.x * blockDim.x + threadIdx.x;
    int stride = gridDim.x * blockDim.x;
    for (; e < E; e += stride) {
        int d = dst[e];
        int pos = off[d] + atomicAdd(&cursor[d], 1);
        csr_src[pos] = src[e];
        csr_eid[pos] = e;
    }
}

// ---------------- per-batch mean of edge_attr ----------------
#define MEAN_BLOCKS_PER_B 64
__global__ void k_mean(const float* __restrict__ eattr, float* __restrict__ meanb) {
    int b   = blockIdx.x / MEAN_BLOCKS_PER_B;
    int blk = blockIdx.x % MEAN_BLOCKS_PER_B;
    int per = (E + MEAN_BLOCKS_PER_B - 1) / MEAN_BLOCKS_PER_B;
    int lo = blk * per;
    int hi = lo + per; if (hi > E) hi = E;
    float s = 0.f;
    for (int i = lo + threadIdx.x; i < hi; i += blockDim.x)
        s += eattr[(size_t)b * E + i];
    __shared__ float sh[256];
    sh[threadIdx.x] = s;
    __syncthreads();
    for (int d = 128; d > 0; d >>= 1) {
        if (threadIdx.x < d) sh[threadIdx.x] += sh[threadIdx.x + d];
        __syncthreads();
    }
    if (threadIdx.x == 0) atomicAdd(&meanb[b], sh[0]);
}

// ---------------- scalar c_edge = dot(lin_edge, att_edge) ----------------
__global__ void k_cedge(const float* __restrict__ lin_edge,
                        const float* __restrict__ att_edge, float* __restrict__ c) {
    if (threadIdx.x == 0) {
        float s = 0.f;
        for (int f = 0; f < F; ++f) s += lin_edge[f] * att_edge[f];
        *c = s;
    }
}

// ---------------- h = x @ W  (fp32, LDS-tiled) ----------------
// 256 rows / block; thread tile 4 rows x 8 cols.
#define XS_LD 260   // padded leading dim (16B-aligned rows, low bank conflict)
__global__ __launch_bounds__(256) void k_gemm(const float* __restrict__ x,
                                              const float* __restrict__ W,
                                              float* __restrict__ h) {
    __shared__ float Ws[DIN * F];      // 16 KB
    __shared__ float xs[32 * XS_LD];   // 33.3 KB, transposed chunk [k][row]
    int t = threadIdx.x;
    int row0 = blockIdx.x * 256;
    // stage W (whole 128x32)
    #pragma unroll
    for (int j = 0; j < 4; ++j) {
        int idx = (t + 256 * j) * 4;
        *(float4*)&Ws[idx] = *(const float4*)&W[idx];
    }
    const int lr = t & 63;   // row-group 0..63  -> rows lr*4 .. lr*4+3
    const int fg = t >> 6;   // 0..3             -> cols fg*8 .. fg*8+7
    float acc[4][8];
    #pragma unroll
    for (int i = 0; i < 4; ++i)
        #pragma unroll
        for (int j = 0; j < 8; ++j) acc[i][j] = 0.f;

    for (int kc = 0; kc < 4; ++kc) {          // 4 chunks of 32 k
        __syncthreads();
        #pragma unroll
        for (int j = 0; j < 8; ++j) {
            int p = t + 256 * j;              // 2048 float4 tiles
            int row = p >> 3;
            int kk  = (p & 7) * 4;
            float4 g = *(const float4*)&x[(size_t)(row0 + row) * DIN + kc * 32 + kk];
            xs[(kk + 0) * XS_LD + row] = g.x;
            xs[(kk + 1) * XS_LD + row] = g.y;
            xs[(kk + 2) * XS_LD + row] = g.z;
            xs[(kk + 3) * XS_LD + row] = g.w;
        }
        __syncthreads();
        #pragma unroll
        for (int k = 0; k < 32; ++k) {
            float4 xv = *(float4*)&xs[k * XS_LD + 4 * lr];
            float4 w0 = *(float4*)&Ws[(kc * 32 + k) * F + fg * 8];
            float4 w1 = *(float4*)&Ws[(kc * 32 + k) * F + fg * 8 + 4];
            float xr[4] = {xv.x, xv.y, xv.z, xv.w};
            float wr[8] = {w0.x, w0.y, w0.z, w0.w, w1.x, w1.y, w1.z, w1.w};
            #pragma unroll
            for (int i = 0; i < 4; ++i)
                #pragma unroll
                for (int j = 0; j < 8; ++j)
                    acc[i][j] = fmaf(xr[i], wr[j], acc[i][j]);
        }
    }
    #pragma unroll
    for (int i = 0; i < 4; ++i) {
        size_t row = (size_t)row0 + lr * 4 + i;
        float4 o0 = {acc[i][0], acc[i][1], acc[i][2], acc[i][3]};
        float4 o1 = {acc[i][4], acc[i][5], acc[i][6], acc[i][7]};
        *(float4*)&h[row * F + fg * 8]     = o0;
        *(float4*)&h[row * F + fg * 8 + 4] = o1;
    }
}

// ---------------- a_src / a_dst = h . att ----------------
__global__ void k_adot(const float* __restrict__ h, const float* __restrict__ att_src,
                       const float* __restrict__ att_dst,
                       float* __restrict__ a_src, float* __restrict__ a_dst) {
    int r = blockIdx.x * blockDim.x + threadIdx.x;
    if (r >= B * N) return;
    const float* hr = &h[(size_t)r * F];
    float s1 = 0.f, s2 = 0.f;
    #pragma unroll
    for (int f = 0; f < F; ++f) {
        float v = hr[f];
        s1 = fmaf(v, att_src[f], s1);
        s2 = fmaf(v, att_dst[f], s2);
    }
    a_src[r] = s1;
    a_dst[r] = s2;
}

// ---------------- online segment-softmax + rep ----------------
// one 32-lane group per (b, dst-node) segment; lane = feature
__global__ __launch_bounds__(256) void k_softmax_rep(
    const float* __restrict__ h, const float* __restrict__ a_src,
    const float* __restrict__ a_dst, const float* __restrict__ eattr,
    const float* __restrict__ bias, const float* __restrict__ meanb,
    const float* __restrict__ cedge, const int* __restrict__ dst_off,
    const int* __restrict__ csr_src, const int* __restrict__ csr_eid,
    float* __restrict__ rep) {
    int seg = blockIdx.x * (blockDim.x >> 5) + (threadIdx.x >> 5);
    if (seg >= B * N) return;
    int lane = threadIdx.x & 31;
    int b = seg / N;
    int i = seg - b * N;
    float c     = *cedge;
    float meanv = meanb[b] * (1.f / (float)E);
    float adst_i = a_dst[(size_t)b * N + i];
    float asrc_i = a_src[(size_t)b * N + i];
    // self loop first (segments are never empty)
    float al = asrc_i + adst_i + meanv * c;
    al = al > 0.f ? al : NEG * al;
    float m = al, s = 1.f;
    float acc = h[((size_t)b * N + i) * F + lane];
    int lo = dst_off[i], hi = dst_off[i + 1];
    for (int j = lo; j < hi; ++j) {
        int sj = csr_src[j];
        int ej = csr_eid[j];
        float a = a_src[(size_t)b * N + sj] + adst_i + eattr[(size_t)b * E + ej] * c;
        a = a > 0.f ? a : NEG * a;
        float hv = h[((size_t)b * N + sj) * F + lane];
        if (a > m) {                      // lane-uniform branch
            float f = __expf(m - a);
            s   = fmaf(s, f, 1.f);
            acc = fmaf(acc, f, hv);
            m = a;
        } else {
            float w = __expf(a - m);
            s += w;
            acc = fmaf(w, hv, acc);
        }
    }
    rep[((size_t)b * N + i) * F + lane] = acc / s + bias[lane];
}

// ---------------- regulon pooling: out[r] = rep[r] + sum_{src=r} rep[dst] ----------------
__global__ __launch_bounds__(256) void k_pool(const float* __restrict__ rep,
                                              const int* __restrict__ roff,
                                              const int* __restrict__ edge_dst,
                                              float* __restrict__ out) {
    int seg = blockIdx.x * (blockDim.x >> 5) + (threadIdx.x >> 5);
    if (seg >= B * NREG) return;
    int lane = threadIdx.x & 31;
    int b = seg / NREG;
    int r = seg - b * NREG;
    float acc = rep[((size_t)b * N + r) * F + lane];
    int lo = roff[r], hi = roff[r + 1];
    for (int e = lo; e < hi; ++e) {
        int d = edge_dst[e];
        acc += rep[((size_t)b * N + d) * F + lane];
    }
    out[((size_t)b * NREG + r) * F + lane] = acc;
}

extern "C" void kernel_launch(void* const* d_in, const int* in_sizes, int n_in,
                              void* d_out, int out_size, void* d_ws, size_t ws_size,
                              hipStream_t stream) {
    const float* x        = (const float*)d_in[0];
    const float* eattr    = (const float*)d_in[1];
    const float* W        = (const float*)d_in[2];
    const float* att_src  = (const float*)d_in[3];
    const float* att_dst  = (const float*)d_in[4];
    const float* lin_edge = (const float*)d_in[5];
    const float* att_edge = (const float*)d_in[6];
    const float* bias     = (const float*)d_in[7];
    const int*   esrc     = (const int*)d_in[8];
    const int*   edst     = (const int*)d_in[9];
    float* out = (float*)d_out;

    char* ws = (char*)d_ws;
    size_t off = 0;
    auto alloc = [&](size_t bytes) -> void* {
        void* p = ws + off;
        off = (off + bytes + 255) & ~(size_t)255;
        return p;
    };
    float* h     = (float*)alloc((size_t)B * N * F * 4);   // 40.96 MB
    float* rep   = (float*)alloc((size_t)B * N * F * 4);   // 40.96 MB
    float* a_src = (float*)alloc((size_t)B * N * 4);
    float* a_dst = (float*)alloc((size_t)B * N * 4);
    int* dst_off = (int*)alloc((size_t)(N + 1) * 4);
    int* roff    = (int*)alloc((size_t)(NREG + 1) * 4);
    int* csr_src = (int*)alloc((size_t)E * 4);
    int* csr_eid = (int*)alloc((size_t)E * 4);
    // region that must start at zero every launch:
    char* zbase   = ws + off;
    int* counts   = (int*)alloc((size_t)N * 4);
    int* rcounts  = (int*)alloc((size_t)NREG * 4);
    int* cursor   = (int*)alloc((size_t)N * 4);
    float* meanb  = (float*)alloc((size_t)B * 4);
    float* cedge  = (float*)alloc(4);
    size_t zbytes = (size_t)((ws + off) - zbase);
    hipMemsetAsync(zbase, 0, zbytes, stream);

    k_hist<<<512, 256, 0, stream>>>(esrc, edst, counts, rcounts);
    k_scan<<<1, 1024, 0, stream>>>(counts, dst_off, N);
    k_scan<<<1, 1024, 0, stream>>>(rcounts, roff, NREG);
    k_scatter<<<512, 256, 0, stream>>>(esrc, edst, dst_off, cursor, csr_src, csr_eid);
    k_mean<<<B * MEAN_BLOCKS_PER_B, 256, 0, stream>>>(eattr, meanb);
    k_cedge<<<1, 64, 0, stream>>>(lin_edge, att_edge, cedge);
    k_gemm<<<(B * N) / 256, 256, 0, stream>>>(x, W, h);
    k_adot<<<(B * N + 255) / 256, 256, 0, stream>>>(h, att_src, att_dst, a_src, a_dst);
    k_softmax_rep<<<(B * N + 7) / 8, 256, 0, stream>>>(h, a_src, a_dst, eattr, bias,
                                                       meanb, cedge, dst_off,
                                                       csr_src, csr_eid, rep);
    k_pool<<<(B * NREG + 7) / 8, 256, 0, stream>>>(rep, roff, edst, out);
}

// Round 2
// 1372.700 us; speedup vs baseline: 1.1663x; 1.1663x over previous
//
#include <hip/hip_runtime.h>
#include <math.h>

#define B    16
#define N    20000
#define E    640000
#define NREG 2000
#define DIN  128
#define F    32
#define NEG  0.2f
#define BF   (B * F)          // 512: one (b,f) plane per node row
#define PSPLIT 8

// ---------------- histogram of edge endpoints ----------------
__global__ void k_hist(const int* __restrict__ src, const int* __restrict__ dst,
                       int* __restrict__ counts, int* __restrict__ rcounts) {
    int e = blockIdx.x * blockDim.x + threadIdx.x;
    int stride = gridDim.x * blockDim.x;
    for (; e < E; e += stride) {
        atomicAdd(&counts[dst[e]], 1);
        atomicAdd(&rcounts[src[e]], 1);
    }
}

// ---------------- single-block exclusive scan ----------------
__global__ void k_scan(const int* __restrict__ in, int* __restrict__ out, int n) {
    __shared__ int sh[1024];
    int t = threadIdx.x;
    int chunk = (n + 1023) / 1024;
    int lo = t * chunk;
    int hi = lo + chunk; if (hi > n) hi = n;
    int local = 0;
    for (int i = lo; i < hi; ++i) local += in[i];
    sh[t] = local;
    __syncthreads();
    for (int d = 1; d < 1024; d <<= 1) {
        int v = (t >= d) ? sh[t - d] : 0;
        __syncthreads();
        sh[t] += v;
        __syncthreads();
    }
    int run = (t == 0) ? 0 : sh[t - 1];
    for (int i = lo; i < hi && i <= n; ++i) { out[i] = run; run += in[i]; }
    if (t == 1023) out[n] = sh[1023];
}

// ---------------- scatter edges into CSR-by-dst ----------------
__global__ void k_scatter(const int* __restrict__ src, const int* __restrict__ dst,
                          const int* __restrict__ off, int* __restrict__ cursor,
                          int* __restrict__ csr_src, int* __restrict__ csr_eid) {
    int e = blockIdx.x * blockDim.x + threadIdx.x;
    int stride = gridDim.x * blockDim.x;
    for (; e < E; e += stride) {
        int d = dst[e];
        int pos = off[d] + atomicAdd(&cursor[d], 1);
        csr_src[pos] = src[e];
        csr_eid[pos] = e;
    }
}

// ---------------- per-batch mean of edge_attr ----------------
#define MEAN_BLOCKS_PER_B 64
__global__ void k_mean(const float* __restrict__ eattr, float* __restrict__ meanb) {
    int b   = blockIdx.x / MEAN_BLOCKS_PER_B;
    int blk = blockIdx.x % MEAN_BLOCKS_PER_B;
    int per = (E + MEAN_BLOCKS_PER_B - 1) / MEAN_BLOCKS_PER_B;
    int lo = blk * per;
    int hi = lo + per; if (hi > E) hi = E;
    float s = 0.f;
    for (int i = lo + threadIdx.x; i < hi; i += blockDim.x)
        s += eattr[(size_t)b * E + i];
    __shared__ float sh[256];
    sh[threadIdx.x] = s;
    __syncthreads();
    for (int d = 128; d > 0; d >>= 1) {
        if (threadIdx.x < d) sh[threadIdx.x] += sh[threadIdx.x + d];
        __syncthreads();
    }
    if (threadIdx.x == 0) atomicAdd(&meanb[b], sh[0]);
}

// ---------------- scalar c_edge = dot(lin_edge, att_edge) ----------------
__global__ void k_cedge(const float* __restrict__ lin_edge,
                        const float* __restrict__ att_edge, float* __restrict__ c) {
    if (threadIdx.x == 0) {
        float s = 0.f;
        for (int f = 0; f < F; ++f) s += lin_edge[f] * att_edge[f];
        *c = s;
    }
}

// ---------------- transpose eattr [B][E] -> et [E][B] ----------------
__global__ __launch_bounds__(256) void k_transpose(const float* __restrict__ eattr,
                                                   float* __restrict__ et) {
    __shared__ float tile[B][257];
    int e0 = blockIdx.x * 256;
    int t = threadIdx.x;
    #pragma unroll
    for (int b = 0; b < B; ++b)
        tile[b][t] = eattr[(size_t)b * E + e0 + t];
    __syncthreads();
    #pragma unroll
    for (int p = 0; p < 16; ++p) {
        int idx = p * 256 + t;        // linear over 256e x 16b
        int el = idx >> 4;
        int bb = idx & 15;
        et[(size_t)(e0 + el) * B + bb] = tile[bb][el];
    }
}

// ---------------- h = x @ W, h layout [n][B][F] ----------------
#define XS_LD 260
__global__ __launch_bounds__(256) void k_gemm(const float* __restrict__ x,
                                              const float* __restrict__ W,
                                              float* __restrict__ h) {
    __shared__ float Ws[DIN * F];
    __shared__ float xs[32 * XS_LD];
    int t = threadIdx.x;
    int row0 = blockIdx.x * 256;      // flattened (b*N + n)
    #pragma unroll
    for (int j = 0; j < 4; ++j) {
        int idx = (t + 256 * j) * 4;
        *(float4*)&Ws[idx] = *(const float4*)&W[idx];
    }
    const int lr = t & 63;
    const int fg = t >> 6;
    float acc[4][8];
    #pragma unroll
    for (int i = 0; i < 4; ++i)
        #pragma unroll
        for (int j = 0; j < 8; ++j) acc[i][j] = 0.f;

    for (int kc = 0; kc < 4; ++kc) {
        __syncthreads();
        #pragma unroll
        for (int j = 0; j < 8; ++j) {
            int p = t + 256 * j;
            int row = p >> 3;
            int kk  = (p & 7) * 4;
            float4 g = *(const float4*)&x[(size_t)(row0 + row) * DIN + kc * 32 + kk];
            xs[(kk + 0) * XS_LD + row] = g.x;
            xs[(kk + 1) * XS_LD + row] = g.y;
            xs[(kk + 2) * XS_LD + row] = g.z;
            xs[(kk + 3) * XS_LD + row] = g.w;
        }
        __syncthreads();
        #pragma unroll
        for (int k = 0; k < 32; ++k) {
            float4 xv = *(float4*)&xs[k * XS_LD + 4 * lr];
            float4 w0 = *(float4*)&Ws[(kc * 32 + k) * F + fg * 8];
            float4 w1 = *(float4*)&Ws[(kc * 32 + k) * F + fg * 8 + 4];
            float xr[4] = {xv.x, xv.y, xv.z, xv.w};
            float wr[8] = {w0.x, w0.y, w0.z, w0.w, w1.x, w1.y, w1.z, w1.w};
            #pragma unroll
            for (int i = 0; i < 4; ++i)
                #pragma unroll
                for (int j = 0; j < 8; ++j)
                    acc[i][j] = fmaf(xr[i], wr[j], acc[i][j]);
        }
    }
    #pragma unroll
    for (int i = 0; i < 4; ++i) {
        int row = row0 + lr * 4 + i;   // b*N + n
        int b = row / N;
        int n = row - b * N;
        float4 o0 = {acc[i][0], acc[i][1], acc[i][2], acc[i][3]};
        float4 o1 = {acc[i][4], acc[i][5], acc[i][6], acc[i][7]};
        float* hp = &h[(size_t)n * BF + b * F + fg * 8];
        *(float4*)&hp[0] = o0;
        *(float4*)&hp[4] = o1;
    }
}

// ---------------- a_src / a_dst, layout [n][B] ----------------
__global__ void k_adot(const float* __restrict__ h, const float* __restrict__ att_src,
                       const float* __restrict__ att_dst,
                       float* __restrict__ a_src, float* __restrict__ a_dst) {
    int i = blockIdx.x * blockDim.x + threadIdx.x;   // n*B + b
    if (i >= N * B) return;
    const float* hr = &h[(size_t)i * F];
    float s1 = 0.f, s2 = 0.f;
    #pragma unroll
    for (int f = 0; f < F; f += 4) {
        float4 v = *(const float4*)&hr[f];
        s1 = fmaf(v.x, att_src[f], fmaf(v.y, att_src[f+1], fmaf(v.z, att_src[f+2], fmaf(v.w, att_src[f+3], s1))));
        s2 = fmaf(v.x, att_dst[f], fmaf(v.y, att_dst[f+1], fmaf(v.z, att_dst[f+2], fmaf(v.w, att_dst[f+3], s2))));
    }
    a_src[i] = s1;
    a_dst[i] = s2;
}

// ---------------- batched two-pass segment softmax + rep ----------------
// one block (512 threads = 16 b x 32 f) per dst node i; all batches at once
__global__ __launch_bounds__(512) void k_softmax2(
    const float* __restrict__ h, const float* __restrict__ a_src,
    const float* __restrict__ a_dst, const float* __restrict__ et,
    const float* __restrict__ bias, const float* __restrict__ meanb,
    const float* __restrict__ cedge, const int* __restrict__ dst_off,
    const int* __restrict__ csr_src, const int* __restrict__ csr_eid,
    float* __restrict__ rep) {
    int i = blockIdx.x;
    int t = threadIdx.x;
    int b = t >> 5;
    int f = t & 31;
    float c = *cedge;
    float meanv = meanb[b] * (1.f / (float)E);
    float adst_i = a_dst[(size_t)i * B + b];
    float asrc_i = a_src[(size_t)i * B + b];
    int lo = dst_off[i], hi = dst_off[i + 1];

    // self-loop alpha
    float al = asrc_i + adst_i + meanv * c;
    al = al > 0.f ? al : NEG * al;

    // pass 1: max (scalar loads only, broadcast across the 32 f-lanes)
    float m = al;
    for (int j = lo; j < hi; ++j) {
        int sj = csr_src[j];
        int ej = csr_eid[j];
        float a = a_src[(size_t)sj * B + b] + adst_i + et[(size_t)ej * B + b] * c;
        a = a > 0.f ? a : NEG * a;
        m = fmaxf(m, a);
    }

    // pass 2: exp-weighted accumulate (no loop-carried rescale)
    float s = __expf(al - m);
    float acc = s * h[(size_t)i * BF + t];
    for (int j = lo; j < hi; ++j) {
        int sj = csr_src[j];
        int ej = csr_eid[j];
        float a = a_src[(size_t)sj * B + b] + adst_i + et[(size_t)ej * B + b] * c;
        a = a > 0.f ? a : NEG * a;
        float w = __expf(a - m);
        s += w;
        acc = fmaf(w, h[(size_t)sj * BF + t], acc);
    }
    rep[(size_t)i * BF + t] = acc / s + bias[f];
}

// ---------------- regulon pooling ----------------
// PSPLIT blocks per regulon; contiguous 2KB rep rows; atomic combine
__global__ __launch_bounds__(512) void k_pool2(const float* __restrict__ rep,
                                               const int* __restrict__ roff,
                                               const int* __restrict__ edge_dst,
                                               float* __restrict__ out) {
    int r    = blockIdx.x / PSPLIT;
    int part = blockIdx.x % PSPLIT;
    int t = threadIdx.x;
    int lo0 = roff[r], hi0 = roff[r + 1];
    int len = hi0 - lo0;
    int lo = lo0 + (int)(((long long)len * part) / PSPLIT);
    int hi = lo0 + (int)(((long long)len * (part + 1)) / PSPLIT);
    float acc = (part == 0) ? rep[(size_t)r * BF + t] : 0.f;
    for (int e = lo; e < hi; ++e) {
        int d = edge_dst[e];
        acc += rep[(size_t)d * BF + t];
    }
    if (part == 0 || lo < hi) {
        int b = t >> 5;
        int f = t & 31;
        atomicAdd(&out[(size_t)b * NREG * F + r * F + f], acc);
    }
}

extern "C" void kernel_launch(void* const* d_in, const int* in_sizes, int n_in,
                              void* d_out, int out_size, void* d_ws, size_t ws_size,
                              hipStream_t stream) {
    const float* x        = (const float*)d_in[0];
    const float* eattr    = (const float*)d_in[1];
    const float* W        = (const float*)d_in[2];
    const float* att_src  = (const float*)d_in[3];
    const float* att_dst  = (const float*)d_in[4];
    const float* lin_edge = (const float*)d_in[5];
    const float* att_edge = (const float*)d_in[6];
    const float* bias     = (const float*)d_in[7];
    const int*   esrc     = (const int*)d_in[8];
    const int*   edst     = (const int*)d_in[9];
    float* out = (float*)d_out;

    char* ws = (char*)d_ws;
    size_t off = 0;
    auto alloc = [&](size_t bytes) -> void* {
        void* p = ws + off;
        off = (off + bytes + 255) & ~(size_t)255;
        return p;
    };
    float* h     = (float*)alloc((size_t)N * BF * 4);      // 41 MB [n][B][F]
    float* rep   = (float*)alloc((size_t)N * BF * 4);      // 41 MB [n][B][F]
    float* et    = (float*)alloc((size_t)E * B * 4);       // 41 MB [e][B]
    float* a_src = (float*)alloc((size_t)N * B * 4);       // [n][B]
    float* a_dst = (float*)alloc((size_t)N * B * 4);
    int* dst_off = (int*)alloc((size_t)(N + 1) * 4);
    int* roff    = (int*)alloc((size_t)(NREG + 1) * 4);
    int* csr_src = (int*)alloc((size_t)E * 4);
    int* csr_eid = (int*)alloc((size_t)E * 4);
    char* zbase   = ws + off;
    int* counts   = (int*)alloc((size_t)N * 4);
    int* rcounts  = (int*)alloc((size_t)NREG * 4);
    int* cursor   = (int*)alloc((size_t)N * 4);
    float* meanb  = (float*)alloc((size_t)B * 4);
    float* cedge  = (float*)alloc(4);
    size_t zbytes = (size_t)((ws + off) - zbase);
    hipMemsetAsync(zbase, 0, zbytes, stream);
    hipMemsetAsync(out, 0, (size_t)out_size * 4, stream);

    k_hist<<<512, 256, 0, stream>>>(esrc, edst, counts, rcounts);
    k_scan<<<1, 1024, 0, stream>>>(counts, dst_off, N);
    k_scan<<<1, 1024, 0, stream>>>(rcounts, roff, NREG);
    k_scatter<<<512, 256, 0, stream>>>(esrc, edst, dst_off, cursor, csr_src, csr_eid);
    k_mean<<<B * MEAN_BLOCKS_PER_B, 256, 0, stream>>>(eattr, meanb);
    k_cedge<<<1, 64, 0, stream>>>(lin_edge, att_edge, cedge);
    k_transpose<<<E / 256, 256, 0, stream>>>(eattr, et);
    k_gemm<<<(B * N) / 256, 256, 0, stream>>>(x, W, h);
    k_adot<<<(N * B + 255) / 256, 256, 0, stream>>>(h, att_src, att_dst, a_src, a_dst);
    k_softmax2<<<N, 512, 0, stream>>>(h, a_src, a_dst, et, bias, meanb, cedge,
                                      dst_off, csr_src, csr_eid, rep);
    k_pool2<<<NREG * PSPLIT, 512, 0, stream>>>(rep, roff, edst, out);
}

// Round 3
// 1167.439 us; speedup vs baseline: 1.3713x; 1.1758x over previous
//
#include <hip/hip_runtime.h>
#include <math.h>

#define B    16
#define N    20000
#define E    640000
#define NREG 2000
#define DIN  128
#define F    32
#define NEG  0.2f
#define BF   (B * F)          // 512
#define PSPLIT 8

// ---------------- histogram of edge endpoints ----------------
__global__ void k_hist(const int* __restrict__ src, const int* __restrict__ dst,
                       int* __restrict__ counts, int* __restrict__ rcounts) {
    int e = blockIdx.x * blockDim.x + threadIdx.x;
    int stride = gridDim.x * blockDim.x;
    for (; e < E; e += stride) {
        atomicAdd(&counts[dst[e]], 1);
        atomicAdd(&rcounts[src[e]], 1);
    }
}

// ---------------- single-block exclusive scan ----------------
__global__ void k_scan(const int* __restrict__ in, int* __restrict__ out, int n) {
    __shared__ int sh[1024];
    int t = threadIdx.x;
    int chunk = (n + 1023) / 1024;
    int lo = t * chunk;
    int hi = lo + chunk; if (hi > n) hi = n;
    int local = 0;
    for (int i = lo; i < hi; ++i) local += in[i];
    sh[t] = local;
    __syncthreads();
    for (int d = 1; d < 1024; d <<= 1) {
        int v = (t >= d) ? sh[t - d] : 0;
        __syncthreads();
        sh[t] += v;
        __syncthreads();
    }
    int run = (t == 0) ? 0 : sh[t - 1];
    for (int i = lo; i < hi; ++i) { out[i] = run; run += in[i]; }
    if (t == 1023) out[n] = sh[1023];
}

// ---------------- scatter edges into CSR-by-dst ----------------
__global__ void k_scatter(const int* __restrict__ src, const int* __restrict__ dst,
                          const int* __restrict__ off, int* __restrict__ cursor,
                          int* __restrict__ csr_src, int* __restrict__ csr_dst,
                          int* __restrict__ pos_of_e) {
    int e = blockIdx.x * blockDim.x + threadIdx.x;
    int stride = gridDim.x * blockDim.x;
    for (; e < E; e += stride) {
        int d = dst[e];
        int pos = off[d] + atomicAdd(&cursor[d], 1);
        csr_src[pos] = src[e];
        csr_dst[pos] = d;
        pos_of_e[e] = pos;
    }
}

// ---------------- per-batch mean of edge_attr ----------------
#define MEAN_BLOCKS_PER_B 64
__global__ void k_mean(const float* __restrict__ eattr, float* __restrict__ meanb) {
    int b   = blockIdx.x / MEAN_BLOCKS_PER_B;
    int blk = blockIdx.x % MEAN_BLOCKS_PER_B;
    int per = (E + MEAN_BLOCKS_PER_B - 1) / MEAN_BLOCKS_PER_B;
    int lo = blk * per;
    int hi = lo + per; if (hi > E) hi = E;
    float s = 0.f;
    for (int i = lo + threadIdx.x; i < hi; i += blockDim.x)
        s += eattr[(size_t)b * E + i];
    __shared__ float sh[256];
    sh[threadIdx.x] = s;
    __syncthreads();
    for (int d = 128; d > 0; d >>= 1) {
        if (threadIdx.x < d) sh[threadIdx.x] += sh[threadIdx.x + d];
        __syncthreads();
    }
    if (threadIdx.x == 0) atomicAdd(&meanb[b], sh[0]);
}

// ---------------- scalar c_edge = dot(lin_edge, att_edge) ----------------
__global__ void k_cedge(const float* __restrict__ lin_edge,
                        const float* __restrict__ att_edge, float* __restrict__ c) {
    if (threadIdx.x == 0) {
        float s = 0.f;
        for (int f = 0; f < F; ++f) s += lin_edge[f] * att_edge[f];
        *c = s;
    }
}

// ---------------- transpose eattr [B][E] -> wbuf[csr_pos][B] ----------------
__global__ __launch_bounds__(256) void k_transpose(const float* __restrict__ eattr,
                                                   const int* __restrict__ pos_of_e,
                                                   float* __restrict__ wbuf) {
    __shared__ float tile[B][257];
    __shared__ int ps[256];
    int e0 = blockIdx.x * 256;
    int t = threadIdx.x;
    #pragma unroll
    for (int b = 0; b < B; ++b)
        tile[b][t] = eattr[(size_t)b * E + e0 + t];
    ps[t] = pos_of_e[e0 + t];
    __syncthreads();
    #pragma unroll
    for (int p = 0; p < 16; ++p) {
        int idx = p * 256 + t;
        int el = idx >> 4;
        int bb = idx & 15;
        wbuf[(size_t)ps[el] * B + bb] = tile[bb][el];
    }
}

// ---------------- h = x @ W (layout [n][B][F]) + fused a_src/a_dst ----------------
#define XS_LD 260
__global__ __launch_bounds__(256) void k_gemm(const float* __restrict__ x,
                                              const float* __restrict__ W,
                                              const float* __restrict__ att_src,
                                              const float* __restrict__ att_dst,
                                              float* __restrict__ h,
                                              float* __restrict__ a_src,
                                              float* __restrict__ a_dst) {
    __shared__ float Ws[DIN * F];
    __shared__ float xs[32 * XS_LD];
    int t = threadIdx.x;
    int row0 = blockIdx.x * 256;      // flattened b*N + n
    #pragma unroll
    for (int j = 0; j < 4; ++j) {
        int idx = (t + 256 * j) * 4;
        *(float4*)&Ws[idx] = *(const float4*)&W[idx];
    }
    const int lr = t & 63;
    const int fg = t >> 6;            // wave-uniform
    float acc[4][8];
    #pragma unroll
    for (int i = 0; i < 4; ++i)
        #pragma unroll
        for (int j = 0; j < 8; ++j) acc[i][j] = 0.f;

    for (int kc = 0; kc < 4; ++kc) {
        __syncthreads();
        #pragma unroll
        for (int j = 0; j < 8; ++j) {
            int p = t + 256 * j;
            int row = p >> 3;
            int kk  = (p & 7) * 4;
            float4 g = *(const float4*)&x[(size_t)(row0 + row) * DIN + kc * 32 + kk];
            xs[(kk + 0) * XS_LD + row] = g.x;
            xs[(kk + 1) * XS_LD + row] = g.y;
            xs[(kk + 2) * XS_LD + row] = g.z;
            xs[(kk + 3) * XS_LD + row] = g.w;
        }
        __syncthreads();
        #pragma unroll
        for (int k = 0; k < 32; ++k) {
            float4 xv = *(float4*)&xs[k * XS_LD + 4 * lr];
            float4 w0 = *(float4*)&Ws[(kc * 32 + k) * F + fg * 8];
            float4 w1 = *(float4*)&Ws[(kc * 32 + k) * F + fg * 8 + 4];
            float xr[4] = {xv.x, xv.y, xv.z, xv.w};
            float wr[8] = {w0.x, w0.y, w0.z, w0.w, w1.x, w1.y, w1.z, w1.w};
            #pragma unroll
            for (int i = 0; i < 4; ++i)
                #pragma unroll
                for (int j = 0; j < 8; ++j)
                    acc[i][j] = fmaf(xr[i], wr[j], acc[i][j]);
        }
    }
    // store h
    #pragma unroll
    for (int i = 0; i < 4; ++i) {
        int row = row0 + lr * 4 + i;
        int b = row / N;
        int n = row - b * N;
        float4 o0 = {acc[i][0], acc[i][1], acc[i][2], acc[i][3]};
        float4 o1 = {acc[i][4], acc[i][5], acc[i][6], acc[i][7]};
        float* hp = &h[(size_t)n * BF + b * F + fg * 8];
        *(float4*)&hp[0] = o0;
        *(float4*)&hp[4] = o1;
    }
    // fused a_src / a_dst: partial dot over this thread's 8 cols, LDS-reduce over fg
    float* red = xs;                  // reuse (needs 2048 floats)
    __syncthreads();
    #pragma unroll
    for (int i = 0; i < 4; ++i) {
        float s1 = 0.f, s2 = 0.f;
        #pragma unroll
        for (int j = 0; j < 8; ++j) {
            float as = att_src[fg * 8 + j];   // scalar (fg wave-uniform)
            float ad = att_dst[fg * 8 + j];
            s1 = fmaf(acc[i][j], as, s1);
            s2 = fmaf(acc[i][j], ad, s2);
        }
        red[fg * 256 + lr * 4 + i]        = s1;
        red[1024 + fg * 256 + lr * 4 + i] = s2;
    }
    __syncthreads();
    {
        float s1 = red[t] + red[256 + t] + red[512 + t] + red[768 + t];
        float s2 = red[1024 + t] + red[1280 + t] + red[1536 + t] + red[1792 + t];
        int row = row0 + t;
        int b = row / N;
        int n = row - b * N;
        a_src[(size_t)n * B + b] = s1;
        a_dst[(size_t)n * B + b] = s2;
    }
}

// ---------------- edge weights: wbuf[j][b] = exp(leaky(alpha)) in-place ----------------
__global__ __launch_bounds__(256) void k_edgew(const int* __restrict__ csr_src,
                                               const int* __restrict__ csr_dst,
                                               const float* __restrict__ a_src,
                                               const float* __restrict__ a_dst,
                                               const float* __restrict__ cedge,
                                               float* __restrict__ wbuf) {
    int t = threadIdx.x;
    int j = blockIdx.x * 16 + (t >> 4);
    int b = t & 15;
    float c = *cedge;
    int sj = csr_src[j];
    int dj = csr_dst[j];
    float a = a_src[(size_t)sj * B + b] + a_dst[(size_t)dj * B + b]
            + wbuf[(size_t)j * B + b] * c;
    a = a > 0.f ? a : NEG * a;
    wbuf[(size_t)j * B + b] = __expf(a);
}

// ---------------- rep: single-pass weighted aggregate ----------------
__global__ __launch_bounds__(512) void k_rep(
    const float* __restrict__ h, const float* __restrict__ a_src,
    const float* __restrict__ a_dst, const float* __restrict__ wbuf,
    const float* __restrict__ bias, const float* __restrict__ meanb,
    const float* __restrict__ cedge, const int* __restrict__ dst_off,
    const int* __restrict__ csr_src, float* __restrict__ rep) {
    int i = blockIdx.x;
    int t = threadIdx.x;
    int b = t >> 5;
    int f = t & 31;
    float c = *cedge;
    float meanv = meanb[b] * (1.f / (float)E);
    float al = a_src[(size_t)i * B + b] + a_dst[(size_t)i * B + b] + meanv * c;
    al = al > 0.f ? al : NEG * al;
    float s = __expf(al);
    float acc = s * h[(size_t)i * BF + t];
    int lo = dst_off[i], hi = dst_off[i + 1];
    for (int j = lo; j < hi; ++j) {
        int sj = csr_src[j];                    // wave-uniform -> scalar load
        float wv = wbuf[(size_t)j * B + b];
        s += wv;
        acc = fmaf(wv, h[(size_t)sj * BF + t], acc);
    }
    rep[(size_t)i * BF + t] = acc / s + bias[f];
}

// ---------------- regulon pooling: partials (no atomics) ----------------
__global__ __launch_bounds__(512) void k_pool(const float* __restrict__ rep,
                                              const int* __restrict__ roff,
                                              const int* __restrict__ edge_dst,
                                              float* __restrict__ partial) {
    int r    = blockIdx.x / PSPLIT;
    int part = blockIdx.x % PSPLIT;
    int t = threadIdx.x;
    int lo0 = roff[r], hi0 = roff[r + 1];
    int len = hi0 - lo0;
    int lo = lo0 + (int)(((long long)len * part) / PSPLIT);
    int hi = lo0 + (int)(((long long)len * (part + 1)) / PSPLIT);
    float acc = (part == 0) ? rep[(size_t)r * BF + t] : 0.f;
    for (int e = lo; e < hi; ++e) {
        int d = edge_dst[e];                    // wave-uniform -> scalar load
        acc += rep[(size_t)d * BF + t];
    }
    partial[((size_t)r * PSPLIT + part) * BF + t] = acc;
}

__global__ __launch_bounds__(512) void k_combine(const float* __restrict__ partial,
                                                 float* __restrict__ out) {
    int r = blockIdx.x;
    int t = threadIdx.x;
    float s = 0.f;
    #pragma unroll
    for (int p = 0; p < PSPLIT; ++p)
        s += partial[((size_t)r * PSPLIT + p) * BF + t];
    int b = t >> 5;
    int f = t & 31;
    out[(size_t)b * NREG * F + r * F + f] = s;
}

extern "C" void kernel_launch(void* const* d_in, const int* in_sizes, int n_in,
                              void* d_out, int out_size, void* d_ws, size_t ws_size,
                              hipStream_t stream) {
    const float* x        = (const float*)d_in[0];
    const float* eattr    = (const float*)d_in[1];
    const float* W        = (const float*)d_in[2];
    const float* att_src  = (const float*)d_in[3];
    const float* att_dst  = (const float*)d_in[4];
    const float* lin_edge = (const float*)d_in[5];
    const float* att_edge = (const float*)d_in[6];
    const float* bias     = (const float*)d_in[7];
    const int*   esrc     = (const int*)d_in[8];
    const int*   edst     = (const int*)d_in[9];
    float* out = (float*)d_out;

    char* ws = (char*)d_ws;
    size_t off = 0;
    auto alloc = [&](size_t bytes) -> void* {
        void* p = ws + off;
        off = (off + bytes + 255) & ~(size_t)255;
        return p;
    };
    float* h     = (float*)alloc((size_t)N * BF * 4);          // 41 MB [n][B][F]
    float* rep   = (float*)alloc((size_t)N * BF * 4);          // 41 MB [n][B][F]
    float* wbuf  = (float*)alloc((size_t)E * B * 4);           // 41 MB [csr_pos][B]
    float* a_src = (float*)alloc((size_t)N * B * 4);
    float* a_dst = (float*)alloc((size_t)N * B * 4);
    int* dst_off = (int*)alloc((size_t)(N + 1) * 4);
    int* roff    = (int*)alloc((size_t)(NREG + 1) * 4);
    int* csr_src = (int*)alloc((size_t)E * 4);
    int* csr_dst = (int*)alloc((size_t)E * 4);
    int* pos_of_e= (int*)alloc((size_t)E * 4);
    char* zbase   = ws + off;
    int* counts   = (int*)alloc((size_t)N * 4);
    int* rcounts  = (int*)alloc((size_t)NREG * 4);
    int* cursor   = (int*)alloc((size_t)N * 4);
    float* meanb  = (float*)alloc((size_t)B * 4);
    float* cedge  = (float*)alloc(4);
    size_t zbytes = (size_t)((ws + off) - zbase);
    // partial pool buffer aliases wbuf (dead after k_rep): 32.8 MB <= 41 MB
    float* partial = wbuf;

    hipMemsetAsync(zbase, 0, zbytes, stream);

    k_hist<<<512, 256, 0, stream>>>(esrc, edst, counts, rcounts);
    k_scan<<<1, 1024, 0, stream>>>(counts, dst_off, N);
    k_scan<<<1, 1024, 0, stream>>>(rcounts, roff, NREG);
    k_scatter<<<512, 256, 0, stream>>>(esrc, edst, dst_off, cursor,
                                       csr_src, csr_dst, pos_of_e);
    k_mean<<<B * MEAN_BLOCKS_PER_B, 256, 0, stream>>>(eattr, meanb);
    k_cedge<<<1, 64, 0, stream>>>(lin_edge, att_edge, cedge);
    k_transpose<<<E / 256, 256, 0, stream>>>(eattr, pos_of_e, wbuf);
    k_gemm<<<(B * N) / 256, 256, 0, stream>>>(x, W, att_src, att_dst,
                                              h, a_src, a_dst);
    k_edgew<<<E / 16, 256, 0, stream>>>(csr_src, csr_dst, a_src, a_dst,
                                        cedge, wbuf);
    k_rep<<<N, 512, 0, stream>>>(h, a_src, a_dst, wbuf, bias, meanb, cedge,
                                 dst_off, csr_src, rep);
    k_pool<<<NREG * PSPLIT, 512, 0, stream>>>(rep, roff, edst, partial);
    k_combine<<<NREG, 512, 0, stream>>>(partial, out);
}

// Round 4
// 682.298 us; speedup vs baseline: 2.3464x; 1.7110x over previous
//
#include <hip/hip_runtime.h>
#include <math.h>

#define B    16
#define N    20000
#define E    640000
#define NREG 2000
#define DIN  128
#define F    32
#define NEG  0.2f
#define BF   (B * F)          // 512 floats per node row; 256 uints in bf16
#define PSPLIT 8

typedef unsigned int uint;

__device__ inline uint bf16pair(float a, float b) {
    uint ua = __float_as_uint(a); ua = (ua + 0x7fffu + ((ua >> 16) & 1u)) >> 16;
    uint ub = __float_as_uint(b); ub = (ub + 0x7fffu + ((ub >> 16) & 1u)) >> 16;
    return ua | (ub << 16);
}
__device__ inline float bf16lo(uint v) { return __uint_as_float(v << 16); }
__device__ inline float bf16hi(uint v) { return __uint_as_float(v & 0xffff0000u); }

// ---------------- dst histogram (random atomics only) ----------------
__global__ void k_hist(const int* __restrict__ dst, int* __restrict__ counts) {
    int e = blockIdx.x * blockDim.x + threadIdx.x;
    int stride = gridDim.x * blockDim.x;
    for (; e < E; e += stride)
        atomicAdd(&counts[dst[e]], 1);
}

// ---------------- regulon offsets via binary search (esrc sorted) ----------------
__global__ void k_roff(const int* __restrict__ esrc, int* __restrict__ roff) {
    int r = blockIdx.x * blockDim.x + threadIdx.x;
    if (r > NREG) return;
    int lo = 0, hi = E;
    while (lo < hi) {
        int mid = (lo + hi) >> 1;
        if (esrc[mid] < r) lo = mid + 1; else hi = mid;
    }
    roff[r] = lo;
}

// ---------------- single-block exclusive scan ----------------
__global__ void k_scan(const int* __restrict__ in, int* __restrict__ out, int n) {
    __shared__ int sh[1024];
    int t = threadIdx.x;
    int chunk = (n + 1023) / 1024;
    int lo = t * chunk;
    int hi = lo + chunk; if (hi > n) hi = n;
    int local = 0;
    for (int i = lo; i < hi; ++i) local += in[i];
    sh[t] = local;
    __syncthreads();
    for (int d = 1; d < 1024; d <<= 1) {
        int v = (t >= d) ? sh[t - d] : 0;
        __syncthreads();
        sh[t] += v;
        __syncthreads();
    }
    int run = (t == 0) ? 0 : sh[t - 1];
    for (int i = lo; i < hi; ++i) { out[i] = run; run += in[i]; }
    if (t == 1023) out[n] = sh[1023];
}

// ---------------- scatter edges into CSR-by-dst ----------------
__global__ void k_scatter(const int* __restrict__ src, const int* __restrict__ dst,
                          const int* __restrict__ off, int* __restrict__ cursor,
                          int* __restrict__ csr_src, int* __restrict__ pos_of_e) {
    int e = blockIdx.x * blockDim.x + threadIdx.x;
    int stride = gridDim.x * blockDim.x;
    for (; e < E; e += stride) {
        int d = dst[e];
        int pos = off[d] + atomicAdd(&cursor[d], 1);
        csr_src[pos] = src[e];
        pos_of_e[e] = pos;
    }
}

// ---------------- per-batch mean of edge_attr ----------------
#define MEAN_BLOCKS_PER_B 64
__global__ void k_mean(const float* __restrict__ eattr, float* __restrict__ meanb) {
    int b   = blockIdx.x / MEAN_BLOCKS_PER_B;
    int blk = blockIdx.x % MEAN_BLOCKS_PER_B;
    int per = (E + MEAN_BLOCKS_PER_B - 1) / MEAN_BLOCKS_PER_B;
    int lo = blk * per;
    int hi = lo + per; if (hi > E) hi = E;
    float s = 0.f;
    for (int i = lo + threadIdx.x; i < hi; i += blockDim.x)
        s += eattr[(size_t)b * E + i];
    __shared__ float sh[256];
    sh[threadIdx.x] = s;
    __syncthreads();
    for (int d = 128; d > 0; d >>= 1) {
        if (threadIdx.x < d) sh[threadIdx.x] += sh[threadIdx.x + d];
        __syncthreads();
    }
    if (threadIdx.x == 0) atomicAdd(&meanb[b], sh[0]);
}

// ---------------- scalar c_edge = dot(lin_edge, att_edge) ----------------
__global__ void k_cedge(const float* __restrict__ lin_edge,
                        const float* __restrict__ att_edge, float* __restrict__ c) {
    if (threadIdx.x == 0) {
        float s = 0.f;
        for (int f = 0; f < F; ++f) s += lin_edge[f] * att_edge[f];
        *c = s;
    }
}

// ---------------- fused: eattr tile -> alpha -> exp -> wbuf[csr_pos][B] ----------------
__global__ __launch_bounds__(256) void k_edgew(const float* __restrict__ eattr,
                                               const int* __restrict__ esrc,
                                               const int* __restrict__ edst,
                                               const int* __restrict__ pos_of_e,
                                               const float* __restrict__ a_src,
                                               const float* __restrict__ a_dst,
                                               const float* __restrict__ cedge,
                                               float* __restrict__ wbuf) {
    __shared__ float tile[B][257];
    __shared__ int ssrc[256], sdst[256], spos[256];
    int e0 = blockIdx.x * 256;
    int t = threadIdx.x;
    #pragma unroll
    for (int b = 0; b < B; ++b)
        tile[b][t] = eattr[(size_t)b * E + e0 + t];
    ssrc[t] = esrc[e0 + t];
    sdst[t] = edst[e0 + t];
    spos[t] = pos_of_e[e0 + t];
    __syncthreads();
    float c = *cedge;
    #pragma unroll
    for (int p = 0; p < 16; ++p) {
        int idx = p * 256 + t;
        int el = idx >> 4;
        int bb = idx & 15;
        float a = a_src[(size_t)ssrc[el] * B + bb]
                + a_dst[(size_t)sdst[el] * B + bb]
                + tile[bb][el] * c;
        a = a > 0.f ? a : NEG * a;
        wbuf[(size_t)spos[el] * B + bb] = __expf(a);
    }
}

// ---------------- h = x @ W -> bf16 [n][B][F]; fused a_src/a_dst ----------------
#define XS_LD 260
__global__ __launch_bounds__(256) void k_gemm(const float* __restrict__ x,
                                              const float* __restrict__ W,
                                              const float* __restrict__ att_src,
                                              const float* __restrict__ att_dst,
                                              uint* __restrict__ hu,
                                              float* __restrict__ a_src,
                                              float* __restrict__ a_dst) {
    __shared__ float Ws[DIN * F];
    __shared__ float xs[32 * XS_LD];
    int t = threadIdx.x;
    int row0 = blockIdx.x * 256;      // flattened b*N + n
    #pragma unroll
    for (int j = 0; j < 4; ++j) {
        int idx = (t + 256 * j) * 4;
        *(float4*)&Ws[idx] = *(const float4*)&W[idx];
    }
    const int lr = t & 63;
    const int fg = t >> 6;            // wave-uniform
    float acc[4][8];
    #pragma unroll
    for (int i = 0; i < 4; ++i)
        #pragma unroll
        for (int j = 0; j < 8; ++j) acc[i][j] = 0.f;

    for (int kc = 0; kc < 4; ++kc) {
        __syncthreads();
        #pragma unroll
        for (int j = 0; j < 8; ++j) {
            int p = t + 256 * j;
            int row = p >> 3;
            int kk  = (p & 7) * 4;
            float4 g = *(const float4*)&x[(size_t)(row0 + row) * DIN + kc * 32 + kk];
            xs[(kk + 0) * XS_LD + row] = g.x;
            xs[(kk + 1) * XS_LD + row] = g.y;
            xs[(kk + 2) * XS_LD + row] = g.z;
            xs[(kk + 3) * XS_LD + row] = g.w;
        }
        __syncthreads();
        #pragma unroll
        for (int k = 0; k < 32; ++k) {
            float4 xv = *(float4*)&xs[k * XS_LD + 4 * lr];
            float4 w0 = *(float4*)&Ws[(kc * 32 + k) * F + fg * 8];
            float4 w1 = *(float4*)&Ws[(kc * 32 + k) * F + fg * 8 + 4];
            float xr[4] = {xv.x, xv.y, xv.z, xv.w};
            float wr[8] = {w0.x, w0.y, w0.z, w0.w, w1.x, w1.y, w1.z, w1.w};
            #pragma unroll
            for (int i = 0; i < 4; ++i)
                #pragma unroll
                for (int j = 0; j < 8; ++j)
                    acc[i][j] = fmaf(xr[i], wr[j], acc[i][j]);
        }
    }
    // store h in bf16 [n][B*F] (uint = 2 features)
    #pragma unroll
    for (int i = 0; i < 4; ++i) {
        int row = row0 + lr * 4 + i;
        int b = row / N;
        int n = row - b * N;
        uint4 o;
        o.x = bf16pair(acc[i][0], acc[i][1]);
        o.y = bf16pair(acc[i][2], acc[i][3]);
        o.z = bf16pair(acc[i][4], acc[i][5]);
        o.w = bf16pair(acc[i][6], acc[i][7]);
        *(uint4*)&hu[(size_t)n * 256 + b * 16 + fg * 4] = o;
    }
    // fused a_src / a_dst
    float* red = xs;
    __syncthreads();
    #pragma unroll
    for (int i = 0; i < 4; ++i) {
        float s1 = 0.f, s2 = 0.f;
        #pragma unroll
        for (int j = 0; j < 8; ++j) {
            float as = att_src[fg * 8 + j];
            float ad = att_dst[fg * 8 + j];
            s1 = fmaf(acc[i][j], as, s1);
            s2 = fmaf(acc[i][j], ad, s2);
        }
        red[fg * 256 + lr * 4 + i]        = s1;
        red[1024 + fg * 256 + lr * 4 + i] = s2;
    }
    __syncthreads();
    {
        float s1 = red[t] + red[256 + t] + red[512 + t] + red[768 + t];
        float s2 = red[1024 + t] + red[1280 + t] + red[1536 + t] + red[1792 + t];
        int row = row0 + t;
        int b = row / N;
        int n = row - b * N;
        a_src[(size_t)n * B + b] = s1;
        a_dst[(size_t)n * B + b] = s2;
    }
}

// ---------------- rep: weighted aggregate (bf16 h in, bf16 rep out) ----------------
// 256 threads: t = b*16 + fp  (b batch, fp = feature pair)
__global__ __launch_bounds__(256) void k_rep(
    const uint* __restrict__ hu, const float* __restrict__ a_src,
    const float* __restrict__ a_dst, const float* __restrict__ wbuf,
    const float* __restrict__ bias, const float* __restrict__ meanb,
    const float* __restrict__ cedge, const int* __restrict__ dst_off,
    const int* __restrict__ csr_src, uint* __restrict__ repu) {
    int i = blockIdx.x;
    int t = threadIdx.x;
    int b  = t >> 4;
    int fp = t & 15;
    float c = *cedge;
    float meanv = meanb[b] * (1.f / (float)E);
    float al = a_src[(size_t)i * B + b] + a_dst[(size_t)i * B + b] + meanv * c;
    al = al > 0.f ? al : NEG * al;
    float s = __expf(al);
    uint hv = hu[(size_t)i * 256 + t];
    float acc0 = s * bf16lo(hv);
    float acc1 = s * bf16hi(hv);
    int lo = dst_off[i], hi = dst_off[i + 1];
    for (int j = lo; j < hi; ++j) {
        int sj = csr_src[j];                    // uniform -> scalar load
        float wv = wbuf[(size_t)j * B + b];
        uint v = hu[(size_t)sj * 256 + t];
        s += wv;
        acc0 = fmaf(wv, bf16lo(v), acc0);
        acc1 = fmaf(wv, bf16hi(v), acc1);
    }
    float inv = 1.f / s;
    repu[(size_t)i * 256 + t] = bf16pair(acc0 * inv + bias[2 * fp],
                                         acc1 * inv + bias[2 * fp + 1]);
}

// ---------------- regulon pooling: partials (no atomics) ----------------
__global__ __launch_bounds__(256) void k_pool(const uint* __restrict__ repu,
                                              const int* __restrict__ roff,
                                              const int* __restrict__ edge_dst,
                                              float* __restrict__ partial) {
    int r    = blockIdx.x / PSPLIT;
    int part = blockIdx.x % PSPLIT;
    int t = threadIdx.x;
    int lo0 = roff[r], hi0 = roff[r + 1];
    int len = hi0 - lo0;
    int lo = lo0 + (int)(((long long)len * part) / PSPLIT);
    int hi = lo0 + (int)(((long long)len * (part + 1)) / PSPLIT);
    float acc0 = 0.f, acc1 = 0.f;
    if (part == 0) {
        uint v = repu[(size_t)r * 256 + t];
        acc0 = bf16lo(v); acc1 = bf16hi(v);
    }
    for (int e = lo; e < hi; ++e) {
        int d = edge_dst[e];                    // uniform -> scalar load
        uint v = repu[(size_t)d * 256 + t];
        acc0 += bf16lo(v);
        acc1 += bf16hi(v);
    }
    float2 o = {acc0, acc1};
    *(float2*)&partial[((size_t)r * PSPLIT + part) * BF + 2 * t] = o;
}

__global__ __launch_bounds__(256) void k_combine(const float* __restrict__ partial,
                                                 float* __restrict__ out) {
    int r = blockIdx.x;
    int t = threadIdx.x;
    int b  = t >> 4;
    int fp = t & 15;
    float s0 = 0.f, s1 = 0.f;
    #pragma unroll
    for (int p = 0; p < PSPLIT; ++p) {
        float2 v = *(const float2*)&partial[((size_t)r * PSPLIT + p) * BF + 2 * t];
        s0 += v.x; s1 += v.y;
    }
    float2 o = {s0, s1};
    *(float2*)&out[(size_t)b * NREG * F + r * F + 2 * fp] = o;
}

extern "C" void kernel_launch(void* const* d_in, const int* in_sizes, int n_in,
                              void* d_out, int out_size, void* d_ws, size_t ws_size,
                              hipStream_t stream) {
    const float* x        = (const float*)d_in[0];
    const float* eattr    = (const float*)d_in[1];
    const float* W        = (const float*)d_in[2];
    const float* att_src  = (const float*)d_in[3];
    const float* att_dst  = (const float*)d_in[4];
    const float* lin_edge = (const float*)d_in[5];
    const float* att_edge = (const float*)d_in[6];
    const float* bias     = (const float*)d_in[7];
    const int*   esrc     = (const int*)d_in[8];
    const int*   edst     = (const int*)d_in[9];
    float* out = (float*)d_out;

    char* ws = (char*)d_ws;
    size_t off = 0;
    auto alloc = [&](size_t bytes) -> void* {
        void* p = ws + off;
        off = (off + bytes + 255) & ~(size_t)255;
        return p;
    };
    uint*  hu    = (uint*)alloc((size_t)N * 256 * 4);          // 20.5 MB bf16 h
    uint*  repu  = (uint*)alloc((size_t)N * 256 * 4);          // 20.5 MB bf16 rep
    float* wbuf  = (float*)alloc((size_t)E * B * 4);           // 41 MB [csr_pos][B]
    float* a_src = (float*)alloc((size_t)N * B * 4);
    float* a_dst = (float*)alloc((size_t)N * B * 4);
    int* dst_off = (int*)alloc((size_t)(N + 1) * 4);
    int* roff    = (int*)alloc((size_t)(NREG + 1) * 4);
    int* csr_src = (int*)alloc((size_t)E * 4);
    int* pos_of_e= (int*)alloc((size_t)E * 4);
    char* zbase   = ws + off;
    int* counts   = (int*)alloc((size_t)N * 4);
    int* cursor   = (int*)alloc((size_t)N * 4);
    float* meanb  = (float*)alloc((size_t)B * 4);
    float* cedge  = (float*)alloc(4);
    size_t zbytes = (size_t)((ws + off) - zbase);
    float* partial = wbuf;   // alias: wbuf dead after k_rep; 32.8 MB <= 41 MB

    hipMemsetAsync(zbase, 0, zbytes, stream);

    k_hist<<<1024, 256, 0, stream>>>(edst, counts);
    k_scan<<<1, 1024, 0, stream>>>(counts, dst_off, N);
    k_roff<<<(NREG + 256) / 256, 256, 0, stream>>>(esrc, roff);
    k_scatter<<<1024, 256, 0, stream>>>(esrc, edst, dst_off, cursor,
                                        csr_src, pos_of_e);
    k_mean<<<B * MEAN_BLOCKS_PER_B, 256, 0, stream>>>(eattr, meanb);
    k_cedge<<<1, 64, 0, stream>>>(lin_edge, att_edge, cedge);
    k_gemm<<<(B * N) / 256, 256, 0, stream>>>(x, W, att_src, att_dst,
                                              hu, a_src, a_dst);
    k_edgew<<<E / 256, 256, 0, stream>>>(eattr, esrc, edst, pos_of_e,
                                         a_src, a_dst, cedge, wbuf);
    k_rep<<<N, 256, 0, stream>>>(hu, a_src, a_dst, wbuf, bias, meanb, cedge,
                                 dst_off, csr_src, repu);
    k_pool<<<NREG * PSPLIT, 256, 0, stream>>>(repu, roff, edst, partial);
    k_combine<<<NREG, 256, 0, stream>>>(partial, out);
}